// Round 1
// baseline (264.269 us; speedup 1.0000x reference)
//
#include <hip/hip_runtime.h>
#include <hip/hip_bf16.h>
#include <stdint.h>

// R10: identical resubmit of the R9 kernel (261.8 us in prior session).
// Prior round's bench failed at the infrastructure level (container failed
// twice) - no counters captured. Re-running to re-establish baseline +
// rocprof before restructuring k_conv's chunk loop.

using bf16x8 = __attribute__((ext_vector_type(8))) __bf16;
using f32x4  = __attribute__((ext_vector_type(4))) float;

// featT2 layout (R9: CHUNK-MAJOR): featT2[chunk 16][img 16][pos 52*52][64 B].
// pos = i*52+j, row/col 0,51 = zero borders. All data bytes written every call
// by k_featT (interior tiles + border tile); no memset. Chunk-major makes both
// k_featT writes (4 KB contiguous per wave) and k_conv's per-chunk staging
// (~3 KB contiguous row segments) DRAM-page friendly.
#define FT_CHUNK_STRIDE 2768896   // 16 img * 2704 pos * 64 B
// W2 layout: [ci-chunk 16][tap 9][co 48][80 B record] (small, stays padded)
#define W2_CHUNK_B 34560

// ---------- helpers ----------
__device__ __forceinline__ unsigned short f2bf(float f) {
  union { float f; unsigned u; } x; x.f = f;
  unsigned r = x.u + 0x7fffu + ((x.u >> 16) & 1u);   // RNE
  return (unsigned short)(r >> 16);
}

__device__ __forceinline__ void gl_lds16(const void* g, void* l) {
  __builtin_amdgcn_global_load_lds(
      (const __attribute__((address_space(1))) void*)g,
      (__attribute__((address_space(3))) void*)l, 16, 0, 0);
}

__device__ __forceinline__ float sl1(float d) {
  float ad = fabsf(d);
  return ad < 1.f ? 0.5f * d * d : ad - 0.5f;
}
__device__ __forceinline__ float softplus_f(float x) {
  return fmaxf(x, 0.f) + log1pf(expf(-fabsf(x)));
}

// strict-fp anchor + IoU: identical bits in weff2-iou and k_loss (no contraction
// possible through __f*_rn intrinsics) so the (iou == max) test is exact.
__device__ __forceinline__ void anchor_strict(int n, float& ax1, float& ay1,
                                              float& ax2, float& ay2) {
  int ii = n / 450;
  int rem = n - ii * 450;
  int jj = rem / 9;
  int a  = rem - jj * 9;
  const float SC[3] = {2.f, 4.f, 6.f};
  const float RA[3] = {0.5f, 1.f, 1.5f};
  float w = __fmul_rn(SC[a % 3], RA[a / 3]);
  float h = SC[a % 3];
  float cx = __fadd_rn((float)ii, 0.5f);
  float cy = __fadd_rn((float)jj, 0.5f);
  float wh = __fmul_rn(w, 0.5f), hh = __fmul_rn(h, 0.5f);
  ax1 = fminf(fmaxf(__fsub_rn(cx, wh), 0.f), 50.f);
  ax2 = fminf(fmaxf(__fadd_rn(cx, wh), 0.f), 50.f);
  ay1 = fminf(fmaxf(__fsub_rn(cy, hh), 0.f), 50.f);
  ay2 = fminf(fmaxf(__fadd_rn(cy, hh), 0.f), 50.f);
}
__device__ __forceinline__ float iou_strict(float ax1, float ay1, float ax2, float ay2,
                                            float aarea, const float* __restrict__ g) {
  float gx1 = __fmul_rn(g[0], 0.0625f), gy1 = __fmul_rn(g[1], 0.0625f);
  float gx2 = __fmul_rn(g[2], 0.0625f), gy2 = __fmul_rn(g[3], 0.0625f);
  float ix1 = fmaxf(ax1, gx1), iy1 = fmaxf(ay1, gy1);
  float ix2 = fminf(ax2, gx2), iy2 = fminf(ay2, gy2);
  float inter = __fmul_rn(fmaxf(__fsub_rn(ix2, ix1), 0.f),
                          fmaxf(__fsub_rn(iy2, iy1), 0.f));
  float garea = __fmul_rn(__fsub_rn(gx2, gx1), __fsub_rn(gy2, gy1));
  float denom = __fadd_rn(__fsub_rn(__fadd_rn(aarea, garea), inter), 1e-8f);
  return __fdiv_rn(inter, denom);
}

// ---------- 1. features NCHW fp32 -> chunk-major packed bf16 (LDS transpose) ----------
// grid (21, 4, 16): x = 128-pos tile (20 = border-zero), y = 128-ci group, z = image.
// Read: lanes along pos -> wave-load = 2 x 512 B contiguous.
// Write: consecutive threads = consecutive pos in ONE chunk plane -> 4 KB
// contiguous per wave (R8 was 256 B segments at 1 KB stride -> page-bound).
__global__ __launch_bounds__(256) void k_featT(const float* __restrict__ feat,
                                               char* __restrict__ featT2) {
  const int tile = blockIdx.x;
  const int g    = blockIdx.y;            // ci group: chunks g*4..g*4+3
  const int b    = blockIdx.z;
  const int tid  = threadIdx.x;
  if (tile == 20) {                       // border: zero 204 positions' chunks
    uint4 z = {0, 0, 0, 0};
    for (int u = tid; u < 204 * 4; u += 256) {
      int p = u & 255; if (p >= 204) p -= 204;     // u%204 without div
      int c4 = u / 204;
      int ip, jp;
      if (p < 52)       { ip = 0;       jp = p; }
      else if (p < 104) { ip = 51;      jp = p - 52; }
      else if (p < 154) { ip = p - 103; jp = 0; }
      else              { ip = p - 153; jp = 51; }
      char* dst = featT2 + (size_t)(g * 4 + c4) * FT_CHUNK_STRIDE
                + (size_t)(b * 2704 + ip * 52 + jp) * 64;
      *(uint4*)(dst)      = z;
      *(uint4*)(dst + 16) = z;
      *(uint4*)(dst + 32) = z;
      *(uint4*)(dst + 48) = z;
    }
    return;
  }
  __shared__ __align__(16) unsigned short sT[128 * 132];  // row stride 264 B
  const int pos0 = tile * 128;
  const float* fb = feat + (size_t)b * 1280000 + (size_t)(g * 128) * 2500;
  const int pq = tid & 31;                // pos quad: pos0 + pq*4 .. +3
  const int rg = tid >> 5;                // ci row-group (4 rows), 0..7
  const int p  = pos0 + pq * 4;
#pragma unroll
  for (int it = 0; it < 4; ++it) {
    int cb = it * 32 + rg * 4;            // ci within group
    float vv[4][4];
#pragma unroll
    for (int q = 0; q < 4; ++q) {
      const float* src = fb + (size_t)(cb + q) * 2500 + p;
      if (p + 3 < 2500) {
        float4 v = *(const float4*)src;
        vv[q][0] = v.x; vv[q][1] = v.y; vv[q][2] = v.z; vv[q][3] = v.w;
      } else {
#pragma unroll
        for (int e = 0; e < 4; ++e)
          vv[q][e] = fb[(size_t)(cb + q) * 2500 + min(p + e, 2499)];
      }
    }
#pragma unroll
    for (int pp = 0; pp < 4; ++pp) {
      ushort4 pk;
      pk.x = f2bf(vv[0][pp]); pk.y = f2bf(vv[1][pp]);
      pk.z = f2bf(vv[2][pp]); pk.w = f2bf(vv[3][pp]);
      *(ushort4*)&sT[(pq * 4 + pp) * 132 + cb] = pk;
    }
  }
  __syncthreads();
#pragma unroll
  for (int q2 = 0; q2 < 2; ++q2) {
    int u = tid + q2 * 256;
    int ch = u >> 7, pr = u & 127;        // consecutive threads -> consecutive pos
    int gp = pos0 + pr;
    if (gp >= 2500) continue;
    int i = gp / 50, j = gp - i * 50;
    char* dst = featT2 + (size_t)(g * 4 + ch) * FT_CHUNK_STRIDE
              + (size_t)(b * 2704 + (i + 1) * 52 + (j + 1)) * 64;
    const uint4* src = (const uint4*)&sT[pr * 132 + ch * 32];
    uint4 a0 = src[0], a1 = src[1], a2 = src[2], a3 = src[3];
    *(uint4*)(dst)      = a0;
    *(uint4*)(dst + 16) = a1;
    *(uint4*)(dst + 32) = a2;
    *(uint4*)(dst + 48) = a3;
  }
}

// ---------- 2a. compose partials (+ zero mx/accum: replaces memset dispatch) ----------
__global__ __launch_bounds__(128) void k_weff1(const float* __restrict__ w1,
                                               const float* __restrict__ wc,
                                               const float* __restrict__ wb,
                                               float* __restrict__ part,
                                               unsigned* __restrict__ zbuf) {
  const int t = threadIdx.x;
  if (blockIdx.x == 0 && blockIdx.y == 0) {   // zero mx(256)+accum(8) dwords
    for (int idx = t; idx < 264; idx += 128) zbuf[idx] = 0u;
  }
  __shared__ float sW[48][64];
  const int kmem = blockIdx.x * 128 + t;
  const int cz = blockIdx.y;
#pragma unroll
  for (int q = 0; q < 24; ++q) {
    int idx = t + q * 128;
    int co = idx >> 6, cl = idx & 63;
    int c = cz * 64 + cl;
    float v = 0.f;
    if (co < 9) v = wc[co * 512 + c];
    else if (co < 45) v = wb[(co - 9) * 512 + c];
    sW[co][cl] = v;
  }
  __syncthreads();
  float acc[48];
#pragma unroll
  for (int co = 0; co < 48; ++co) acc[co] = 0.f;
  const float* w1p = w1 + (size_t)(cz * 64) * 4608 + kmem;
  for (int c4 = 0; c4 < 64; c4 += 4) {
    float f0 = w1p[(size_t)(c4 + 0) * 4608];
    float f1 = w1p[(size_t)(c4 + 1) * 4608];
    float f2 = w1p[(size_t)(c4 + 2) * 4608];
    float f3 = w1p[(size_t)(c4 + 3) * 4608];
#pragma unroll
    for (int co = 0; co < 48; ++co) {
      float4 wv = *(const float4*)&sW[co][c4];
      acc[co] += wv.x * f0 + wv.y * f1 + wv.z * f2 + wv.w * f3;
    }
  }
  float* dst = part + (size_t)cz * 221184 + kmem;
#pragma unroll
  for (int co = 0; co < 48; ++co) dst[(size_t)co * 4608] = acc[co];
}

// ---------- 2b. blocks <1080: reduce partials -> W2; 1080..1127: bias;
//              blocks >=1128: per-(b,gt) max IoU (folded k_iou dispatch) ----------
__global__ __launch_bounds__(256) void k_weff2(const float* __restrict__ part,
                                               unsigned short* __restrict__ w2,
                                               const float* __restrict__ wc,
                                               const float* __restrict__ wb,
                                               const float* __restrict__ b1,
                                               const float* __restrict__ bc,
                                               const float* __restrict__ bbx,
                                               float* __restrict__ bias_eff,
                                               const float* __restrict__ gt_boxes,
                                               unsigned* __restrict__ mx) {
  if (blockIdx.x >= 1128) {                  // IoU max pass
    int q = blockIdx.x - 1128;               // 0..1407
    int b = q / 88, nb = q - b * 88;
    int n = nb * 256 + threadIdx.x;
    float lm[16];
#pragma unroll
    for (int m = 0; m < 16; ++m) lm[m] = 0.f;
    if (n < 22500) {
      float ax1, ay1, ax2, ay2;
      anchor_strict(n, ax1, ay1, ax2, ay2);
      float aarea = __fmul_rn(__fsub_rn(ax2, ax1), __fsub_rn(ay2, ay1));
#pragma unroll
      for (int m = 0; m < 16; ++m)
        lm[m] = iou_strict(ax1, ay1, ax2, ay2, aarea, gt_boxes + (b * 16 + m) * 4);
    }
    __shared__ float red[4][16];
#pragma unroll
    for (int m = 0; m < 16; ++m) {
      float v = lm[m];
      for (int o = 32; o; o >>= 1) v = fmaxf(v, __shfl_down(v, o, 64));
      if ((threadIdx.x & 63) == 0) red[threadIdx.x >> 6][m] = v;
    }
    __syncthreads();
    if (threadIdx.x < 16) {
      float v = fmaxf(fmaxf(red[0][threadIdx.x], red[1][threadIdx.x]),
                      fmaxf(red[2][threadIdx.x], red[3][threadIdx.x]));
      atomicMax(mx + b * 16 + threadIdx.x, __float_as_uint(v));
    }
    return;
  }
  if (blockIdx.x >= 1080) {                  // bias_eff[co] = b_head + whead·b1
    int co = blockIdx.x - 1080;
    int l = threadIdx.x;
    if (l >= 64) return;
    float s = 0.f;
#pragma unroll
    for (int q = 0; q < 8; ++q) {
      int c = q * 64 + l;
      float wv = co < 9 ? wc[co * 512 + c] : (co < 45 ? wb[(co - 9) * 512 + c] : 0.f);
      s += wv * b1[c];
    }
    for (int o = 32; o; o >>= 1) s += __shfl_down(s, o, 64);
    if (l == 0)
      bias_eff[co] = s + (co < 9 ? bc[co] : (co < 45 ? bbx[co - 9] : 0.f));
    return;
  }
  int idx = blockIdx.x * 256 + threadIdx.x;   // < 276480 = 16*9*48*40
  int c = idx / 17280;  int r = idx - c * 17280;
  int tap = r / 1920;   int r2 = r - tap * 1920;
  int co = r2 / 40;     int e = r2 - co * 40;
  float s = 0.f;
  if (e < 32) {
    int ci = c * 32 + e;
    const float* p = part + (size_t)co * 4608 + ci * 9 + tap;
#pragma unroll
    for (int cz = 0; cz < 8; ++cz) s += p[(size_t)cz * 221184];
  }
  w2[idx] = f2bf(s);
}

// ---------- 3. direct conv+head: spatial tiles, all 9 taps from LDS ----------
__global__ __launch_bounds__(256) void k_conv(const char* __restrict__ featT2,
                                              const char* __restrict__ w2,
                                              const float* __restrict__ beff,
                                              float* __restrict__ oh) {
  __shared__ __align__(16) char sF[2][19456];   // 225*80=18000 used; 18*1024 staged
  __shared__ __align__(16) char sA[2][34816];   // 9*48*80=34560; 34*1024 staged
  const int tid = threadIdx.x, lane = tid & 63, w = tid >> 6;
  const int bx = blockIdx.x;
  const int b = bx >> 4, tl = bx & 15, tr = tl >> 2, tc = tl & 3;
  const int i0 = tr * 13 - (tr == 3 ? 1 : 0);   // {0,13,26,38}
  const int TI = (tr >= 2) ? 12 : 13;
  const int j0 = tc * 13 - (tc == 3 ? 1 : 0);
  const int TJ = (tc >= 2) ? 12 : 13;
  const int TJ2 = TJ + 2;
  const int mcount = TI * TJ;
  const int pieces = (TI + 2) * TJ2 * 5;        // LDS 16B pieces per chunk

  // sF staging: LDS piece pi -> (pos, pc); pc==4 is the LDS pad piece, staged
  // as a duplicate of piece 3 — never read. Chunk-major: stage adds c*stride.
  const char* srcF[5];
#pragma unroll
  for (int k = 0; k < 5; ++k) {
    int s = w * 5 + k;
    int pi = s * 64 + lane;
    if (pi >= pieces) pi = pieces - 1;
    int pos = pi / 5, pc = pi - pos * 5;
    if (pc > 3) pc = 3;
    int hi = pos / TJ2, hj = pos - hi * TJ2;
    srcF[k] = featT2 + (size_t)(b * 2704 + (i0 + hi) * 52 + (j0 + hj)) * 64 + pc * 16;
  }
  int idxB[3];
#pragma unroll
  for (int bf = 0; bf < 3; ++bf) {
    int p = (w * 3 + bf) * 16 + (lane & 15);
    if (p >= mcount) p = mcount - 1;
    int di = p / TJ, dj = p - di * TJ;
    idxB[bf] = (di * TJ2 + dj) * 80 + (lane >> 4) * 16;
  }
  const int aoff = (lane & 15) * 80 + (lane >> 4) * 16;
  int toff[9];
#pragma unroll
  for (int tp = 0; tp < 9; ++tp) toff[tp] = ((tp / 3) * TJ2 + (tp % 3)) * 80;

  f32x4 acc[3][3] = {};

  auto stage = [&](int c, int pb) {
    size_t coff = (size_t)c * FT_CHUNK_STRIDE;
#pragma unroll
    for (int k = 0; k < 5; ++k) {
      int s = w * 5 + k;
      if (s < 18) gl_lds16(srcF[k] + coff, sF[pb] + s * 1024);
    }
#pragma unroll
    for (int k = 0; k < 9; ++k) {
      int s = w + 4 * k;
      if (s < 34)
        gl_lds16(w2 + (size_t)c * W2_CHUNK_B + s * 1024 + lane * 16, sA[pb] + s * 1024);
    }
  };

  stage(0, 0);
  __builtin_amdgcn_s_waitcnt(0);
  __syncthreads();

  for (int c = 0; c < 16; ++c) {
    int pb = c & 1;
    if (c < 15) stage(c + 1, pb ^ 1);
    const char* fA = sA[pb];
    const char* fB = sF[pb];
#pragma unroll
    for (int tp = 0; tp < 9; ++tp) {
      bf16x8 av[3], bv[3];
#pragma unroll
      for (int cf = 0; cf < 3; ++cf)
        av[cf] = *(const bf16x8*)(fA + tp * 3840 + cf * 1280 + aoff);
#pragma unroll
      for (int bf = 0; bf < 3; ++bf)
        bv[bf] = *(const bf16x8*)(fB + idxB[bf] + toff[tp]);
#pragma unroll
      for (int cf = 0; cf < 3; ++cf)
#pragma unroll
        for (int bf = 0; bf < 3; ++bf)
          acc[cf][bf] = __builtin_amdgcn_mfma_f32_16x16x32_bf16(av[cf], bv[bf], acc[cf][bf], 0, 0, 0);
    }
    __builtin_amdgcn_s_waitcnt(0);
    __syncthreads();
  }

  f32x4 bias[3];
#pragma unroll
  for (int cf = 0; cf < 3; ++cf)
    bias[cf] = *(const f32x4*)(beff + cf * 16 + (lane >> 4) * 4);
#pragma unroll
  for (int bf = 0; bf < 3; ++bf) {
    int p = (w * 3 + bf) * 16 + (lane & 15);
    if (p >= mcount) continue;
    int di = p / TJ, dj = p - di * TJ;
    int gm = (b * 50 + i0 + di) * 50 + (j0 + dj);
#pragma unroll
    for (int cf = 0; cf < 3; ++cf) {
      f32x4 v = acc[cf][bf];
#pragma unroll
      for (int r = 0; r < 4; ++r) v[r] += bias[cf][r];
      *(f32x4*)(oh + (size_t)gm * 48 + cf * 16 + (lane >> 4) * 4) = v;
    }
  }
}

// ---------- 4. loss pass: recompute IoU (strict), loss sums, proposals ----------
__global__ __launch_bounds__(256) void k_loss(const float* __restrict__ gt_boxes,
                                              const unsigned* __restrict__ mxbuf,
                                              const float* __restrict__ oh,
                                              float* __restrict__ accum,
                                              float* __restrict__ dout) {
  int b = blockIdx.y;
  int n = blockIdx.x * 256 + threadIdx.x;
  float s_np = 0.f, s_reg = 0.f, s_pos = 0.f, s_nc = 0.f, s_nl = 0.f;
  if (n < 22500) {
    float ax1, ay1, ax2, ay2;
    anchor_strict(n, ax1, ay1, ax2, ay2);
    float aarea = __fmul_rn(__fsub_rn(ax2, ax1), __fsub_rn(ay2, ay1));
    float acx = (ax1 + ax2) * 0.5f, acy = (ay1 + ay2) * 0.5f;
    float aw = fmaxf(ax2 - ax1, 1e-6f), ah = fmaxf(ay2 - ay1, 1e-6f);
    int ii = n / 450, rem = n - ii * 450, jj = rem / 9, a = rem - jj * 9;
    const float* row = oh + ((size_t)(b * 2500 + ii * 50 + jj)) * 48;
    float logit = row[a];
    float p0 = row[9 + a * 4], p1 = row[10 + a * 4];
    float p2 = row[11 + a * 4], p3 = row[12 + a * 4];
    int npos = 0;
    bool allneg = true;
#pragma unroll
    for (int m = 0; m < 16; ++m) {
      const float* g = gt_boxes + (b * 16 + m) * 4;
      float iou = iou_strict(ax1, ay1, ax2, ay2, aarea, g);
      float mxv = __uint_as_float(mxbuf[b * 16 + m]);
      bool pos = ((iou == mxv) && (mxv > 0.f)) || (iou > 0.7f);
      if (iou >= 0.3f) allneg = false;
      if (pos) {
        ++npos;
        float gx1 = g[0] * 0.0625f, gy1 = g[1] * 0.0625f;
        float gx2 = g[2] * 0.0625f, gy2 = g[3] * 0.0625f;
        float gcx = (gx1 + gx2) * 0.5f, gcy = (gy1 + gy2) * 0.5f;
        float gw = fmaxf(gx2 - gx1, 1e-6f), gh = fmaxf(gy2 - gy1, 1e-6f);
        float tx = (gcx - acx) / aw, ty = (gcy - acy) / ah;
        float twv = logf(gw / aw), thv = logf(gh / ah);
        s_reg += sl1(tx - p0) + sl1(ty - p1) + sl1(twv - p2) + sl1(thv - p3);
      }
    }
    s_np = (float)npos;
    s_pos = (float)npos * softplus_f(-logit);
    if (allneg) { s_nc = 1.f; s_nl = softplus_f(logit); }
    float pcx = acx + p0 * aw, pcy = acy + p1 * ah;
    float pw = aw * expf(p2), ph = ah * expf(p3);
    float* o = dout + 1 + ((size_t)b * 22500 + n) * 4;
    o[0] = pcx - pw * 0.5f;
    o[1] = pcy - ph * 0.5f;
    o[2] = pcx + pw * 0.5f;
    o[3] = pcy + ph * 0.5f;
  }
  float vals[5] = {s_np, s_reg, s_pos, s_nc, s_nl};
  __shared__ float red[4][5];
#pragma unroll
  for (int q = 0; q < 5; ++q) {
    float v = vals[q];
    for (int o = 32; o; o >>= 1) v += __shfl_down(v, o, 64);
    if ((threadIdx.x & 63) == 0) red[threadIdx.x >> 6][q] = v;
  }
  __syncthreads();
  if (threadIdx.x < 5) {
    float v = red[0][threadIdx.x] + red[1][threadIdx.x] +
              red[2][threadIdx.x] + red[3][threadIdx.x];
    atomicAdd(accum + threadIdx.x, v);
  }
}

// ---------- 5. finalize ----------
__global__ void k_fin(const float* __restrict__ accum, float* __restrict__ dout) {
  if (threadIdx.x == 0 && blockIdx.x == 0) {
    float np = fmaxf(accum[0], 1.f);
    float nn = fmaxf(accum[3], 1.f);
    float loss = 0.5f * (accum[2] / np + accum[4] / nn) + 5.f * (accum[1] / (4.f * np));
    dout[0] = loss;
  }
}

// ---------- launch ----------
extern "C" void kernel_launch(void* const* d_in, const int* in_sizes, int n_in,
                              void* d_out, int out_size, void* d_ws, size_t ws_size,
                              hipStream_t stream) {
  const float* features = (const float*)d_in[0];
  const float* gt_boxes = (const float*)d_in[1];
  const float* w1    = (const float*)d_in[2];
  const float* b1    = (const float*)d_in[3];
  const float* w_cls = (const float*)d_in[4];
  const float* b_cls = (const float*)d_in[5];
  const float* w_box = (const float*)d_in[6];
  const float* b_box = (const float*)d_in[7];
  float* out = (float*)d_out;
  char* ws = (char*)d_ws;

  // ws layout (featT2 chunk-major: 16*16*2704*64 = 44,302,336 B)
  char*           featT2 = ws;                                  // 44,302,336 B
  unsigned short* w2     = (unsigned short*)(ws + 44302336);    //    552,960 B
  float*          wpart  = (float*)(ws + 44855296);             //  7,077,888 B
  float*          oh     = (float*)(ws + 51933184);             //  7,680,000 B
  float*          beff   = (float*)(ws + 59613184);             //        192 B
  unsigned*       mx     = (unsigned*)(ws + 59613376);          //      1,024 B
  float*          accum  = (float*)(ws + 59614400);             //         32 B

  k_featT<<<dim3(21, 4, 16), 256, 0, stream>>>(features, featT2);
  k_weff1<<<dim3(36, 8), 128, 0, stream>>>(w1, w_cls, w_box, wpart, mx);
  k_weff2<<<2536, 256, 0, stream>>>(wpart, w2, w_cls, w_box, b1, b_cls, b_box,
                                    beff, gt_boxes, mx);
  k_conv<<<256, 256, 0, stream>>>(featT2, (const char*)w2, beff, oh);
  k_loss<<<dim3(88, 16), 256, 0, stream>>>(gt_boxes, mx, oh, accum, out);
  k_fin<<<1, 64, 0, stream>>>(accum, out);
}